// Round 13
// baseline (340.598 us; speedup 1.0000x reference)
//
#include <hip/hip_runtime.h>
#include <cfloat>
#include <math.h>

#define NUM_EMB 8192
#define DIM 256
#define NROWS 32768
#define NSPLIT 4
#define CHUNKS 32   // (8192 / NSPLIT) / 64 cols per chunk

typedef float f32x4 __attribute__((ext_vector_type(4)));
typedef int   i32x4 __attribute__((ext_vector_type(4)));
typedef int   i32x8 __attribute__((ext_vector_type(8)));

#define GL2LDS(g, l) __builtin_amdgcn_global_load_lds( \
    (const __attribute__((address_space(1))) void*)(g), \
    (__attribute__((address_space(3))) void*)(l), 16, 0, 0)

#define MFMA(A, B, C) __builtin_amdgcn_mfma_scale_f32_16x16x128_f8f6f4( \
    (A), (B), (C), 0, 0, 0, 127, 0, 127)

// volatile ds_read_b128: forced issue order + forced-live destination regs.
#define DSR(dst, addr, IMM) \
    asm volatile("ds_read_b128 %0, %1 offset:%2" : "=v"(dst) : "v"(addr), "n"(IMM))

// ---------------- prep: x -> -x in fp8 ; codebook -> fp8(e*8192) + half-scaled biased norms ; zero counts/acc ----------------
__global__ __launch_bounds__(256) void vq_prep(const float* __restrict__ x,
                                               unsigned char* __restrict__ xq,
                                               const float* __restrict__ cb,
                                               unsigned char* __restrict__ cbq,
                                               float* __restrict__ cbn,
                                               unsigned int* __restrict__ counts,
                                               double* __restrict__ acc,
                                               unsigned int* __restrict__ ticket) {
    int b = blockIdx.x;
    if (b < 2048) {
        // x-quant: 2 groups of 8 floats per thread (64B read / 16B write)
        #pragma unroll
        for (int j = 0; j < 2; j++) {
            int i = b * 512 + j * 256 + threadIdx.x;
            float4 v0 = ((const float4*)x)[2 * i];
            float4 v1 = ((const float4*)x)[2 * i + 1];
            // store NEGATED x: MFMA with C=bn/2 accumulates bn/2 - x.(8192e) = score/2 directly
            int p0 = __builtin_amdgcn_cvt_pk_fp8_f32(-v0.x, -v0.y, 0, false);
            p0     = __builtin_amdgcn_cvt_pk_fp8_f32(-v0.z, -v0.w, p0, true);
            int p1 = __builtin_amdgcn_cvt_pk_fp8_f32(-v1.x, -v1.y, 0, false);
            p1     = __builtin_amdgcn_cvt_pk_fp8_f32(-v1.z, -v1.w, p1, true);
            ((int2*)xq)[i] = make_int2(p0, p1);
        }
    } else if (b < 4096) {
        int row  = (b - 2048) * 4 + (threadIdx.x >> 6);
        int lane = threadIdx.x & 63;
        float4 v = ((const float4*)(cb + (size_t)row * DIM))[lane];
        // store e*8192 in fp8 (range (-1,1)); scale folds out of the argmin
        int p = __builtin_amdgcn_cvt_pk_fp8_f32(v.x * 8192.f, v.y * 8192.f, 0, false);
        p     = __builtin_amdgcn_cvt_pk_fp8_f32(v.z * 8192.f, v.w * 8192.f, p, true);
        ((int*)cbq)[row * 64 + lane] = p;
        float s = v.x * v.x + v.y * v.y + v.z * v.z + v.w * v.w;
        #pragma unroll
        for (int off = 32; off > 0; off >>= 1) s += __shfl_down(s, off, 64);
        // HALF-scaled norm + 256 bias: score/2 stays positive => u32-monotone float bits
        if (lane == 0) cbn[row] = 4096.f * s + 256.f;
    } else {
        counts[(b - 4096) * 256 + threadIdx.x] = 0u;
        if (b == 4096 && threadIdx.x == 0) {
            acc[0] = 0.0; acc[1] = 0.0; *ticket = 0u;
        }
    }
}

// ---------------- MX-FP8 MFMA GEMM + fused running argmin (r4/r5 kernel + 5-blocks/CU LDS trim) ----------------
// Block: 64 rows x 2048 cols (32 chunks of 64). A-fragments (of -x) in REGISTERS;
// B double-buffered through 2 x 16KB LDS, 2-phase pipeline. The 8 ds_read_b128
// per chunk are volatile inline asm with counted lgkmcnt(4)/(0) waits, each
// followed by sched_barrier(0) (hipcc hoists register-only MFMAs otherwise).
// NEW vs r12: redk is ALIASED onto Bs[0] (dead by epilogue - final chunk's
// __syncthreads orders all LDS reads before redk writes), cutting static LDS
// from 33792 to exactly 32768 B -> 5 blocks/CU (163840/32768 = 5.0), i.e.
// 5 waves/SIMD instead of 4. Cycle model: per SIMD per chunk-period 3225cy,
// MFMA 1104 (34%), VALU ~1355 (42%), residue ~770cy = dependency stalls that
// 4 waves can't fill. Blocks are barrier-independent, so a 5th resident block
// fills other blocks' barrier/wait windows. This is the one untried TLP axis
// (r10's 512-thr variant halved per-wave work instead - wrong lever).
// __launch_bounds__(256,5): min 5 waves/EU caps VGPR at ~102 (currently 60).
// MFMA C operand = bn/2 = 4096||e||^2+256 so acc IS score/2 >= 0:
// running u32 key per (i,r): score[31:11] | ch[10:6] | col[5:0].
__global__ __launch_bounds__(256, 5) void vq_argmin_mfma(
        const unsigned char* __restrict__ xq,
        const unsigned char* __restrict__ cbq,
        const float* __restrict__ cbn,
        unsigned long long* __restrict__ partial) {
    __shared__ __align__(16) unsigned char Bs[2][16384];  // [buf][64 rows][256B], 16B blocks swizzled per 128B half
    // epilogue-only reduction buffer aliased onto Bs[0] (1KB << 16KB)
    unsigned long long (*redk)[64] =
        reinterpret_cast<unsigned long long (*)[64]>(&Bs[0][0]);

    const int tid = threadIdx.x;
    const int lane = tid & 63;
    const int w = tid >> 6;           // wave 0..3
    const int wm = w >> 1, wn = w & 1;
    const int l15 = lane & 15, q = lane >> 4;
    const int ns = blockIdx.x & (NSPLIT - 1);
    const int by = blockIdx.x >> 2;
    const int m0 = by * 64;
    const int nbase = ns * (NUM_EMB / NSPLIT);

    // A fragments in registers: afr[kc][i], 32B/lane = k-bytes kc*128+q*32..+31
    i32x8 afr00, afr01, afr10, afr11;
    {
        const unsigned char* p = xq + (size_t)(m0 + wm * 32 + l15) * 256 + q * 32;
        i32x4 lo, hi;
        lo = *(const i32x4*)(p);                  hi = *(const i32x4*)(p + 16);
        afr00 = __builtin_shufflevector(lo, hi, 0, 1, 2, 3, 4, 5, 6, 7);      // kc0,i0
        lo = *(const i32x4*)(p + 16 * 256);       hi = *(const i32x4*)(p + 16 * 256 + 16);
        afr01 = __builtin_shufflevector(lo, hi, 0, 1, 2, 3, 4, 5, 6, 7);      // kc0,i1
        lo = *(const i32x4*)(p + 128);            hi = *(const i32x4*)(p + 128 + 16);
        afr10 = __builtin_shufflevector(lo, hi, 0, 1, 2, 3, 4, 5, 6, 7);      // kc1,i0
        lo = *(const i32x4*)(p + 16 * 256 + 128); hi = *(const i32x4*)(p + 16 * 256 + 128 + 16);
        afr11 = __builtin_shufflevector(lo, hi, 0, 1, 2, 3, 4, 5, 6, 7);      // kc1,i1
    }

    // LDS read addresses (chunk-invariant; buffer select folds into ds imm offset)
    const int row0 = wn * 32 + l15;               // j=0 codebook row; j=1 = +16 (same &7)
    const int sw = row0 & 7;
    const int vA = row0 * 256 + (((2 * q) ^ sw) * 16);
    const int vB = row0 * 256 + (((2 * q + 1) ^ sw) * 16);
    const unsigned lbase =
        (unsigned)(size_t)(__attribute__((address_space(3))) void*)(void*)&Bs[0][0];
    const int addrA = (int)(lbase + (unsigned)vA);
    const int addrB = (int)(lbase + (unsigned)vB);

    const unsigned int colb0 = (unsigned)(wn * 32 + l15);
    const unsigned int colb1 = colb0 + 16;

    unsigned int runk[2][4];
    #pragma unroll
    for (int i = 0; i < 2; i++)
        #pragma unroll
        for (int r = 0; r < 4; r++) runk[i][r] = 0xFFFFFFFFu;

    // staging: 16 segments of 1KB (4 rows); wave w owns segments {w,4+w,8+w,12+w}
    const int sr = lane >> 4;
    const int sv = lane & 15;
    const int kcs = sv >> 3, blk = sv & 7;
    const unsigned char* gs[4];
    int sg[4];
    #pragma unroll
    for (int t = 0; t < 4; t++) {
        int s = t * 4 + w;
        int r = s * 4 + sr;
        gs[t] = cbq + (size_t)(nbase + r) * 256 + (size_t)(kcs * 128 + ((blk ^ (r & 7)) * 16));
        sg[t] = s * 1024;
    }

    // prologue: stage chunk 0 -> Bs[0]
    #pragma unroll
    for (int t = 0; t < 4; t++) GL2LDS(gs[t], (char*)&Bs[0][0] + sg[t]);
    #pragma unroll
    for (int t = 0; t < 4; t++) gs[t] += 16384;
    const float* bnp = cbn + nbase;
    float bn0 = bnp[colb0];
    float bn1 = bnp[colb1];
    __syncthreads();   // vmcnt(0) drain: Bs[0] ready

#define CHUNK_BODY(CHV, CUR, NXT, LAST) do { \
    float nbn0 = bnp[64 + (int)colb0]; \
    float nbn1 = bnp[64 + (int)colb1]; \
    if (!(LAST)) { \
        GL2LDS(gs[0], (char*)&Bs[NXT][0] + sg[0]); \
        GL2LDS(gs[1], (char*)&Bs[NXT][0] + sg[1]); \
        GL2LDS(gs[2], (char*)&Bs[NXT][0] + sg[2]); \
        GL2LDS(gs[3], (char*)&Bs[NXT][0] + sg[3]); \
        __builtin_amdgcn_sched_barrier(0); \
    } \
    gs[0] += 16384; gs[1] += 16384; gs[2] += 16384; gs[3] += 16384; \
    f32x4 ci0; ci0[0] = bn0; ci0[1] = bn0; ci0[2] = bn0; ci0[3] = bn0; \
    f32x4 ci1; ci1[0] = bn1; ci1[1] = bn1; ci1[2] = bn1; ci1[3] = bn1; \
    i32x4 b0l, b0h, b1l, b1h, b2l, b2h, b3l, b3h; \
    DSR(b0l, addrA, (CUR) * 16384 + 0); \
    DSR(b0h, addrB, (CUR) * 16384 + 0); \
    DSR(b2l, addrA, (CUR) * 16384 + 4096); \
    DSR(b2h, addrB, (CUR) * 16384 + 4096); \
    DSR(b1l, addrA, (CUR) * 16384 + 128); \
    DSR(b1h, addrB, (CUR) * 16384 + 128); \
    DSR(b3l, addrA, (CUR) * 16384 + 4224); \
    DSR(b3h, addrB, (CUR) * 16384 + 4224); \
    asm volatile("s_waitcnt lgkmcnt(4)" ::: "memory"); \
    __builtin_amdgcn_sched_barrier(0); \
    i32x8 b0 = __builtin_shufflevector(b0l, b0h, 0, 1, 2, 3, 4, 5, 6, 7); \
    i32x8 b2 = __builtin_shufflevector(b2l, b2h, 0, 1, 2, 3, 4, 5, 6, 7); \
    f32x4 a00 = MFMA(afr00, b0, ci0); \
    f32x4 a10 = MFMA(afr01, b0, ci0); \
    f32x4 a01 = MFMA(afr00, b2, ci1); \
    f32x4 a11 = MFMA(afr01, b2, ci1); \
    asm volatile("s_waitcnt lgkmcnt(0)" ::: "memory"); \
    __builtin_amdgcn_sched_barrier(0); \
    i32x8 b1 = __builtin_shufflevector(b1l, b1h, 0, 1, 2, 3, 4, 5, 6, 7); \
    i32x8 b3 = __builtin_shufflevector(b3l, b3h, 0, 1, 2, 3, 4, 5, 6, 7); \
    a00 = MFMA(afr10, b1, a00); \
    a10 = MFMA(afr11, b1, a10); \
    a01 = MFMA(afr10, b3, a01); \
    a11 = MFMA(afr11, b3, a11); \
    unsigned int chb = ((unsigned)(CHV)) << 6; \
    unsigned int cj0 = chb | colb0, cj1 = chb | colb1; \
    _Pragma("unroll") \
    for (int r = 0; r < 4; r++) { \
        unsigned int k00 = (__float_as_uint(a00[r]) & 0xFFFFF800u) | cj0; \
        unsigned int k01 = (__float_as_uint(a01[r]) & 0xFFFFF800u) | cj1; \
        runk[0][r] = min(min(k00, k01), runk[0][r]); \
        unsigned int k10 = (__float_as_uint(a10[r]) & 0xFFFFF800u) | cj0; \
        unsigned int k11 = (__float_as_uint(a11[r]) & 0xFFFFF800u) | cj1; \
        runk[1][r] = min(min(k10, k11), runk[1][r]); \
    } \
    bn0 = nbn0; bn1 = nbn1; bnp += 64; \
    __syncthreads(); \
} while (0)

    #pragma unroll 1
    for (int ch = 0; ch < CHUNKS; ch += 2) {
        CHUNK_BODY(ch,     0, 1, false);
        CHUNK_BODY(ch + 1, 1, 0, (ch + 1) == CHUNKS - 1);
    }

    // epilogue once per block: full u64 (score, global col) shuffle-min.
    // redk aliases Bs[0]; the final CHUNK_BODY __syncthreads ordered all LDS
    // reads before these writes.
    #pragma unroll
    for (int i = 0; i < 2; i++) {
        #pragma unroll
        for (int r = 0; r < 4; r++) {
            unsigned int rk = runk[i][r];
            unsigned int gcol = (unsigned)nbase + (rk & 0x7FFu);   // ch*64+col
            unsigned long long key =
                ((unsigned long long)(rk & 0xFFFFF800u) << 32) | gcol;
            #pragma unroll
            for (int off = 8; off >= 1; off >>= 1) {
                unsigned long long o = __shfl_xor(key, off, 16);
                if (o < key) key = o;
            }
            if (l15 == 0) redk[wn][wm * 32 + i * 16 + q * 4 + r] = key;
        }
    }
    __syncthreads();
    if (tid < 64) {
        unsigned long long k0 = redk[0][tid], k1 = redk[1][tid];
        partial[(size_t)ns * NROWS + m0 + tid] = k0 < k1 ? k0 : k1;   // coalesced
    }
}

// ---------------- fused: reduce partials -> gather + outputs + loss + counts ----------------
// 32 rows per block (8 rows per wave); nontemporal out stores (never re-read).
__global__ __launch_bounds__(256) void vq_out(const float* __restrict__ x,
                                              const float* __restrict__ cb,
                                              const unsigned long long* __restrict__ partial,
                                              float* __restrict__ out,
                                              unsigned int* __restrict__ counts,
                                              double* __restrict__ loss_part) {
    __shared__ float wred[4];
    int wv   = threadIdx.x >> 6;
    int lane = threadIdx.x & 63;
    float wsum = 0.f;
    #pragma unroll
    for (int rr = 0; rr < 8; rr++) {
        int row = blockIdx.x * 32 + wv * 8 + rr;
        unsigned long long k = 0xFFFFFFFFFFFFFFFFull;
        #pragma unroll
        for (int t = 0; t < NSPLIT; t++) {
            unsigned long long v = partial[(size_t)t * NROWS + row];
            if (v < k) k = v;
        }
        int id = (int)(unsigned int)(k & 0xffffffffu);   // wave-uniform
        float4 qv = ((const float4*)(cb + (size_t)id * DIM))[lane];
        float4 xv = ((const float4*)(x + (size_t)row * DIM))[lane];
        float dx = qv.x - xv.x, dy = qv.y - xv.y, dz = qv.z - xv.z, dw = qv.w - xv.w;
        f32x4 o;
        o[0] = xv.x + dx; o[1] = xv.y + dy; o[2] = xv.z + dz; o[3] = xv.w + dw;
        __builtin_nontemporal_store(o, (f32x4*)(out + (size_t)row * DIM) + lane);
        float s = dx * dx + dy * dy + dz * dz + dw * dw;
        #pragma unroll
        for (int o2 = 32; o2 > 0; o2 >>= 1) s += __shfl_down(s, o2, 64);
        if (lane == 0) {
            wsum += s;
            atomicAdd(&counts[id], 1u);
        }
    }
    if (lane == 0) wred[wv] = wsum;
    __syncthreads();
    if (threadIdx.x == 0) {
        loss_part[blockIdx.x] =
            (double)wred[0] + (double)wred[1] + (double)wred[2] + (double)wred[3];
    }
}

// ---------------- finalize loss + perplexity: 32 blocks + f64 atomics + ticket ----------------
__global__ __launch_bounds__(256) void vq_fin(const unsigned int* __restrict__ counts,
                                              const double* __restrict__ loss_part,
                                              double* __restrict__ acc,
                                              unsigned int* __restrict__ ticket,
                                              float* __restrict__ out_tail) {
    __shared__ double sh[4];
    __shared__ double sl[4];
    __shared__ unsigned int tk;
    int tid = threadIdx.x, wv = tid >> 6, lane = tid & 63;
    int k = blockIdx.x * 256 + tid;                       // 32*256 = 8192 exactly
    float p = (float)counts[k] * (1.0f / 32768.0f);
    double h = (double)(p * __logf(p + 1e-10f));
    double ls = (tid < 32) ? loss_part[blockIdx.x * 32 + tid] : 0.0;  // 32*32 = 1024
    #pragma unroll
    for (int o = 32; o > 0; o >>= 1) {
        h  += __shfl_down(h,  o, 64);
        ls += __shfl_down(ls, o, 64);
    }
    if (lane == 0) { sh[wv] = h; sl[wv] = ls; }
    __syncthreads();
    if (tid == 0) {
        atomicAdd(&acc[0], sh[0] + sh[1] + sh[2] + sh[3]);
        atomicAdd(&acc[1], sl[0] + sl[1] + sl[2] + sl[3]);
        __threadfence();
        tk = __hip_atomic_fetch_add(ticket, 1u, __ATOMIC_ACQ_REL,
                                    __HIP_MEMORY_SCOPE_AGENT);
    }
    __syncthreads();
    if (tk == 31 && tid == 0) {
        double hs = __hip_atomic_load(&acc[0], __ATOMIC_RELAXED, __HIP_MEMORY_SCOPE_AGENT);
        double lt = __hip_atomic_load(&acc[1], __ATOMIC_RELAXED, __HIP_MEMORY_SCOPE_AGENT);
        double mean = lt / (double)((size_t)NROWS * DIM);
        out_tail[0] = (float)(1.25 * mean);
        out_tail[1] = (float)exp(-hs);
    }
}

extern "C" void kernel_launch(void* const* d_in, const int* in_sizes, int n_in,
                              void* d_out, int out_size, void* d_ws, size_t ws_size,
                              hipStream_t stream) {
    const float* x  = (const float*)d_in[0];
    const float* cb = (const float*)d_in[1];
    char* ws = (char*)d_ws;
    double* acc            = (double*)ws;                               // 16 B
    unsigned int* ticket   = (unsigned int*)(ws + 16);                  // 4 B
    unsigned int* counts   = (unsigned int*)(ws + 256);                 // 32 KB
    float* cbn             = (float*)(ws + 33024);                      // 32 KB
    unsigned char* xq      = (unsigned char*)(ws + 65792);              // 8 MB fp8 -x
    unsigned char* cbq     = (unsigned char*)(ws + 65792 + 8388608);    // 2 MB fp8 e*8192
    unsigned long long* pp = (unsigned long long*)(ws + 65792 + 8388608 + 2097152); // 1 MB
    double* loss_part      = (double*)(ws + 65792 + 8388608 + 2097152 + 16777216);  // 8 KB
    float* out = (float*)d_out;

    vq_prep       <<<4128, 256, 0, stream>>>(x, xq, cb, cbq, cbn, counts, acc, ticket);
    vq_argmin_mfma<<<512 * NSPLIT, 256, 0, stream>>>(xq, cbq, cbn, pp);
    vq_out        <<<1024, 256, 0, stream>>>(x, cb, pp, out, counts, loss_part);
    vq_fin        <<<32, 256, 0, stream>>>(counts, loss_part, acc, ticket,
                                           out + (size_t)NROWS * DIM);
}

// Round 14
// 180.068 us; speedup vs baseline: 1.8915x; 1.8915x over previous
//
#include <hip/hip_runtime.h>
#include <cfloat>
#include <math.h>

#define NUM_EMB 8192
#define DIM 256
#define NROWS 32768
#define NSPLIT 4
#define CHUNKS 32   // (8192 / NSPLIT) / 64 cols per chunk

typedef float f32x4 __attribute__((ext_vector_type(4)));
typedef int   i32x4 __attribute__((ext_vector_type(4)));
typedef int   i32x8 __attribute__((ext_vector_type(8)));

#define GL2LDS(g, l) __builtin_amdgcn_global_load_lds( \
    (const __attribute__((address_space(1))) void*)(g), \
    (__attribute__((address_space(3))) void*)(l), 16, 0, 0)

#define MFMA(A, B, C) __builtin_amdgcn_mfma_scale_f32_16x16x128_f8f6f4( \
    (A), (B), (C), 0, 0, 0, 127, 0, 127)

// volatile ds_read_b128: forced issue order + forced-live destination regs.
#define DSR(dst, addr, IMM) \
    asm volatile("ds_read_b128 %0, %1 offset:%2" : "=v"(dst) : "v"(addr), "n"(IMM))

// ---------------- prep: x -> -x in fp8 ; codebook -> fp8(e*8192) + half-scaled biased norms ; zero counts/acc ----------------
__global__ __launch_bounds__(256) void vq_prep(const float* __restrict__ x,
                                               unsigned char* __restrict__ xq,
                                               const float* __restrict__ cb,
                                               unsigned char* __restrict__ cbq,
                                               float* __restrict__ cbn,
                                               unsigned int* __restrict__ counts,
                                               double* __restrict__ acc,
                                               unsigned int* __restrict__ ticket) {
    int b = blockIdx.x;
    if (b < 2048) {
        // x-quant: 2 groups of 8 floats per thread (64B read / 16B write)
        #pragma unroll
        for (int j = 0; j < 2; j++) {
            int i = b * 512 + j * 256 + threadIdx.x;
            float4 v0 = ((const float4*)x)[2 * i];
            float4 v1 = ((const float4*)x)[2 * i + 1];
            // store NEGATED x: MFMA with C=bn/2 accumulates bn/2 - x.(8192e) = score/2 directly
            int p0 = __builtin_amdgcn_cvt_pk_fp8_f32(-v0.x, -v0.y, 0, false);
            p0     = __builtin_amdgcn_cvt_pk_fp8_f32(-v0.z, -v0.w, p0, true);
            int p1 = __builtin_amdgcn_cvt_pk_fp8_f32(-v1.x, -v1.y, 0, false);
            p1     = __builtin_amdgcn_cvt_pk_fp8_f32(-v1.z, -v1.w, p1, true);
            ((int2*)xq)[i] = make_int2(p0, p1);
        }
    } else if (b < 4096) {
        int row  = (b - 2048) * 4 + (threadIdx.x >> 6);
        int lane = threadIdx.x & 63;
        float4 v = ((const float4*)(cb + (size_t)row * DIM))[lane];
        // store e*8192 in fp8 (range (-1,1)); scale folds out of the argmin
        int p = __builtin_amdgcn_cvt_pk_fp8_f32(v.x * 8192.f, v.y * 8192.f, 0, false);
        p     = __builtin_amdgcn_cvt_pk_fp8_f32(v.z * 8192.f, v.w * 8192.f, p, true);
        ((int*)cbq)[row * 64 + lane] = p;
        float s = v.x * v.x + v.y * v.y + v.z * v.z + v.w * v.w;
        #pragma unroll
        for (int off = 32; off > 0; off >>= 1) s += __shfl_down(s, off, 64);
        // HALF-scaled norm + 256 bias: score/2 stays positive => u32-monotone float bits
        if (lane == 0) cbn[row] = 4096.f * s + 256.f;
    } else {
        counts[(b - 4096) * 256 + threadIdx.x] = 0u;
        if (b == 4096 && threadIdx.x == 0) {
            acc[0] = 0.0; acc[1] = 0.0; *ticket = 0u;
        }
    }
}

// ---------------- MX-FP8 MFMA GEMM + fused running argmin (r12 codegen + 32KB LDS for 5-blocks/CU) ----------------
// Block: 64 rows x 2048 cols (32 chunks of 64). A-fragments (of -x) in REGISTERS;
// B double-buffered through 2 x 16KB LDS, 2-phase pipeline. The 8 ds_read_b128
// per chunk are volatile inline asm with counted lgkmcnt(4)/(0) waits, each
// followed by sched_barrier(0) (hipcc hoists register-only MFMAs otherwise).
// redk is ALIASED onto Bs[0] (dead by epilogue - final chunk's __syncthreads
// orders all LDS reads before redk writes): static LDS = exactly 32768 B ->
// HW can co-schedule 5 blocks/CU (163840/32768 = 5.0).
// r13 LESSON: __launch_bounds__(256,5) made the allocator target VGPR 48 and
// SPILL the A-fragments (FETCH 97MB/WRITE 405MB scratch, MfmaUtil 11%). The
// hint was unnecessary - at VGPR 60, 8 waves/SIMD already fit - so keep the
// r12-proven (256,4) bounds and let the HARDWARE pick up the 5th block from
// the LDS headroom alone. Clean A/B vs r12: only LDS size differs.
// MFMA C operand = bn/2 = 4096||e||^2+256 so acc IS score/2 >= 0:
// running u32 key per (i,r): score[31:11] | ch[10:6] | col[5:0].
__global__ __launch_bounds__(256, 4) void vq_argmin_mfma(
        const unsigned char* __restrict__ xq,
        const unsigned char* __restrict__ cbq,
        const float* __restrict__ cbn,
        unsigned long long* __restrict__ partial) {
    __shared__ __align__(16) unsigned char Bs[2][16384];  // [buf][64 rows][256B], 16B blocks swizzled per 128B half
    // epilogue-only reduction buffer aliased onto Bs[0] (1KB << 16KB)
    unsigned long long (*redk)[64] =
        reinterpret_cast<unsigned long long (*)[64]>(&Bs[0][0]);

    const int tid = threadIdx.x;
    const int lane = tid & 63;
    const int w = tid >> 6;           // wave 0..3
    const int wm = w >> 1, wn = w & 1;
    const int l15 = lane & 15, q = lane >> 4;
    const int ns = blockIdx.x & (NSPLIT - 1);
    const int by = blockIdx.x >> 2;
    const int m0 = by * 64;
    const int nbase = ns * (NUM_EMB / NSPLIT);

    // A fragments in registers: afr[kc][i], 32B/lane = k-bytes kc*128+q*32..+31
    i32x8 afr00, afr01, afr10, afr11;
    {
        const unsigned char* p = xq + (size_t)(m0 + wm * 32 + l15) * 256 + q * 32;
        i32x4 lo, hi;
        lo = *(const i32x4*)(p);                  hi = *(const i32x4*)(p + 16);
        afr00 = __builtin_shufflevector(lo, hi, 0, 1, 2, 3, 4, 5, 6, 7);      // kc0,i0
        lo = *(const i32x4*)(p + 16 * 256);       hi = *(const i32x4*)(p + 16 * 256 + 16);
        afr01 = __builtin_shufflevector(lo, hi, 0, 1, 2, 3, 4, 5, 6, 7);      // kc0,i1
        lo = *(const i32x4*)(p + 128);            hi = *(const i32x4*)(p + 128 + 16);
        afr10 = __builtin_shufflevector(lo, hi, 0, 1, 2, 3, 4, 5, 6, 7);      // kc1,i0
        lo = *(const i32x4*)(p + 16 * 256 + 128); hi = *(const i32x4*)(p + 16 * 256 + 128 + 16);
        afr11 = __builtin_shufflevector(lo, hi, 0, 1, 2, 3, 4, 5, 6, 7);      // kc1,i1
    }

    // LDS read addresses (chunk-invariant; buffer select folds into ds imm offset)
    const int row0 = wn * 32 + l15;               // j=0 codebook row; j=1 = +16 (same &7)
    const int sw = row0 & 7;
    const int vA = row0 * 256 + (((2 * q) ^ sw) * 16);
    const int vB = row0 * 256 + (((2 * q + 1) ^ sw) * 16);
    const unsigned lbase =
        (unsigned)(size_t)(__attribute__((address_space(3))) void*)(void*)&Bs[0][0];
    const int addrA = (int)(lbase + (unsigned)vA);
    const int addrB = (int)(lbase + (unsigned)vB);

    const unsigned int colb0 = (unsigned)(wn * 32 + l15);
    const unsigned int colb1 = colb0 + 16;

    unsigned int runk[2][4];
    #pragma unroll
    for (int i = 0; i < 2; i++)
        #pragma unroll
        for (int r = 0; r < 4; r++) runk[i][r] = 0xFFFFFFFFu;

    // staging: 16 segments of 1KB (4 rows); wave w owns segments {w,4+w,8+w,12+w}
    const int sr = lane >> 4;
    const int sv = lane & 15;
    const int kcs = sv >> 3, blk = sv & 7;
    const unsigned char* gs[4];
    int sg[4];
    #pragma unroll
    for (int t = 0; t < 4; t++) {
        int s = t * 4 + w;
        int r = s * 4 + sr;
        gs[t] = cbq + (size_t)(nbase + r) * 256 + (size_t)(kcs * 128 + ((blk ^ (r & 7)) * 16));
        sg[t] = s * 1024;
    }

    // prologue: stage chunk 0 -> Bs[0]
    #pragma unroll
    for (int t = 0; t < 4; t++) GL2LDS(gs[t], (char*)&Bs[0][0] + sg[t]);
    #pragma unroll
    for (int t = 0; t < 4; t++) gs[t] += 16384;
    const float* bnp = cbn + nbase;
    float bn0 = bnp[colb0];
    float bn1 = bnp[colb1];
    __syncthreads();   // vmcnt(0) drain: Bs[0] ready

#define CHUNK_BODY(CHV, CUR, NXT, LAST) do { \
    float nbn0 = bnp[64 + (int)colb0]; \
    float nbn1 = bnp[64 + (int)colb1]; \
    if (!(LAST)) { \
        GL2LDS(gs[0], (char*)&Bs[NXT][0] + sg[0]); \
        GL2LDS(gs[1], (char*)&Bs[NXT][0] + sg[1]); \
        GL2LDS(gs[2], (char*)&Bs[NXT][0] + sg[2]); \
        GL2LDS(gs[3], (char*)&Bs[NXT][0] + sg[3]); \
        __builtin_amdgcn_sched_barrier(0); \
    } \
    gs[0] += 16384; gs[1] += 16384; gs[2] += 16384; gs[3] += 16384; \
    f32x4 ci0; ci0[0] = bn0; ci0[1] = bn0; ci0[2] = bn0; ci0[3] = bn0; \
    f32x4 ci1; ci1[0] = bn1; ci1[1] = bn1; ci1[2] = bn1; ci1[3] = bn1; \
    i32x4 b0l, b0h, b1l, b1h, b2l, b2h, b3l, b3h; \
    DSR(b0l, addrA, (CUR) * 16384 + 0); \
    DSR(b0h, addrB, (CUR) * 16384 + 0); \
    DSR(b2l, addrA, (CUR) * 16384 + 4096); \
    DSR(b2h, addrB, (CUR) * 16384 + 4096); \
    DSR(b1l, addrA, (CUR) * 16384 + 128); \
    DSR(b1h, addrB, (CUR) * 16384 + 128); \
    DSR(b3l, addrA, (CUR) * 16384 + 4224); \
    DSR(b3h, addrB, (CUR) * 16384 + 4224); \
    asm volatile("s_waitcnt lgkmcnt(4)" ::: "memory"); \
    __builtin_amdgcn_sched_barrier(0); \
    i32x8 b0 = __builtin_shufflevector(b0l, b0h, 0, 1, 2, 3, 4, 5, 6, 7); \
    i32x8 b2 = __builtin_shufflevector(b2l, b2h, 0, 1, 2, 3, 4, 5, 6, 7); \
    f32x4 a00 = MFMA(afr00, b0, ci0); \
    f32x4 a10 = MFMA(afr01, b0, ci0); \
    f32x4 a01 = MFMA(afr00, b2, ci1); \
    f32x4 a11 = MFMA(afr01, b2, ci1); \
    asm volatile("s_waitcnt lgkmcnt(0)" ::: "memory"); \
    __builtin_amdgcn_sched_barrier(0); \
    i32x8 b1 = __builtin_shufflevector(b1l, b1h, 0, 1, 2, 3, 4, 5, 6, 7); \
    i32x8 b3 = __builtin_shufflevector(b3l, b3h, 0, 1, 2, 3, 4, 5, 6, 7); \
    a00 = MFMA(afr10, b1, a00); \
    a10 = MFMA(afr11, b1, a10); \
    a01 = MFMA(afr10, b3, a01); \
    a11 = MFMA(afr11, b3, a11); \
    unsigned int chb = ((unsigned)(CHV)) << 6; \
    unsigned int cj0 = chb | colb0, cj1 = chb | colb1; \
    _Pragma("unroll") \
    for (int r = 0; r < 4; r++) { \
        unsigned int k00 = (__float_as_uint(a00[r]) & 0xFFFFF800u) | cj0; \
        unsigned int k01 = (__float_as_uint(a01[r]) & 0xFFFFF800u) | cj1; \
        runk[0][r] = min(min(k00, k01), runk[0][r]); \
        unsigned int k10 = (__float_as_uint(a10[r]) & 0xFFFFF800u) | cj0; \
        unsigned int k11 = (__float_as_uint(a11[r]) & 0xFFFFF800u) | cj1; \
        runk[1][r] = min(min(k10, k11), runk[1][r]); \
    } \
    bn0 = nbn0; bn1 = nbn1; bnp += 64; \
    __syncthreads(); \
} while (0)

    #pragma unroll 1
    for (int ch = 0; ch < CHUNKS; ch += 2) {
        CHUNK_BODY(ch,     0, 1, false);
        CHUNK_BODY(ch + 1, 1, 0, (ch + 1) == CHUNKS - 1);
    }

    // epilogue once per block: full u64 (score, global col) shuffle-min.
    // redk aliases Bs[0]; the final CHUNK_BODY __syncthreads ordered all LDS
    // reads before these writes.
    #pragma unroll
    for (int i = 0; i < 2; i++) {
        #pragma unroll
        for (int r = 0; r < 4; r++) {
            unsigned int rk = runk[i][r];
            unsigned int gcol = (unsigned)nbase + (rk & 0x7FFu);   // ch*64+col
            unsigned long long key =
                ((unsigned long long)(rk & 0xFFFFF800u) << 32) | gcol;
            #pragma unroll
            for (int off = 8; off >= 1; off >>= 1) {
                unsigned long long o = __shfl_xor(key, off, 16);
                if (o < key) key = o;
            }
            if (l15 == 0) redk[wn][wm * 32 + i * 16 + q * 4 + r] = key;
        }
    }
    __syncthreads();
    if (tid < 64) {
        unsigned long long k0 = redk[0][tid], k1 = redk[1][tid];
        partial[(size_t)ns * NROWS + m0 + tid] = k0 < k1 ? k0 : k1;   // coalesced
    }
}

// ---------------- fused: reduce partials -> gather + outputs + loss + counts ----------------
// 32 rows per block (8 rows per wave); nontemporal out stores (never re-read).
__global__ __launch_bounds__(256) void vq_out(const float* __restrict__ x,
                                              const float* __restrict__ cb,
                                              const unsigned long long* __restrict__ partial,
                                              float* __restrict__ out,
                                              unsigned int* __restrict__ counts,
                                              double* __restrict__ loss_part) {
    __shared__ float wred[4];
    int wv   = threadIdx.x >> 6;
    int lane = threadIdx.x & 63;
    float wsum = 0.f;
    #pragma unroll
    for (int rr = 0; rr < 8; rr++) {
        int row = blockIdx.x * 32 + wv * 8 + rr;
        unsigned long long k = 0xFFFFFFFFFFFFFFFFull;
        #pragma unroll
        for (int t = 0; t < NSPLIT; t++) {
            unsigned long long v = partial[(size_t)t * NROWS + row];
            if (v < k) k = v;
        }
        int id = (int)(unsigned int)(k & 0xffffffffu);   // wave-uniform
        float4 qv = ((const float4*)(cb + (size_t)id * DIM))[lane];
        float4 xv = ((const float4*)(x + (size_t)row * DIM))[lane];
        float dx = qv.x - xv.x, dy = qv.y - xv.y, dz = qv.z - xv.z, dw = qv.w - xv.w;
        f32x4 o;
        o[0] = xv.x + dx; o[1] = xv.y + dy; o[2] = xv.z + dz; o[3] = xv.w + dw;
        __builtin_nontemporal_store(o, (f32x4*)(out + (size_t)row * DIM) + lane);
        float s = dx * dx + dy * dy + dz * dz + dw * dw;
        #pragma unroll
        for (int o2 = 32; o2 > 0; o2 >>= 1) s += __shfl_down(s, o2, 64);
        if (lane == 0) {
            wsum += s;
            atomicAdd(&counts[id], 1u);
        }
    }
    if (lane == 0) wred[wv] = wsum;
    __syncthreads();
    if (threadIdx.x == 0) {
        loss_part[blockIdx.x] =
            (double)wred[0] + (double)wred[1] + (double)wred[2] + (double)wred[3];
    }
}

// ---------------- finalize loss + perplexity: 32 blocks + f64 atomics + ticket ----------------
__global__ __launch_bounds__(256) void vq_fin(const unsigned int* __restrict__ counts,
                                              const double* __restrict__ loss_part,
                                              double* __restrict__ acc,
                                              unsigned int* __restrict__ ticket,
                                              float* __restrict__ out_tail) {
    __shared__ double sh[4];
    __shared__ double sl[4];
    __shared__ unsigned int tk;
    int tid = threadIdx.x, wv = tid >> 6, lane = tid & 63;
    int k = blockIdx.x * 256 + tid;                       // 32*256 = 8192 exactly
    float p = (float)counts[k] * (1.0f / 32768.0f);
    double h = (double)(p * __logf(p + 1e-10f));
    double ls = (tid < 32) ? loss_part[blockIdx.x * 32 + tid] : 0.0;  // 32*32 = 1024
    #pragma unroll
    for (int o = 32; o > 0; o >>= 1) {
        h  += __shfl_down(h,  o, 64);
        ls += __shfl_down(ls, o, 64);
    }
    if (lane == 0) { sh[wv] = h; sl[wv] = ls; }
    __syncthreads();
    if (tid == 0) {
        atomicAdd(&acc[0], sh[0] + sh[1] + sh[2] + sh[3]);
        atomicAdd(&acc[1], sl[0] + sl[1] + sl[2] + sl[3]);
        __threadfence();
        tk = __hip_atomic_fetch_add(ticket, 1u, __ATOMIC_ACQ_REL,
                                    __HIP_MEMORY_SCOPE_AGENT);
    }
    __syncthreads();
    if (tk == 31 && tid == 0) {
        double hs = __hip_atomic_load(&acc[0], __ATOMIC_RELAXED, __HIP_MEMORY_SCOPE_AGENT);
        double lt = __hip_atomic_load(&acc[1], __ATOMIC_RELAXED, __HIP_MEMORY_SCOPE_AGENT);
        double mean = lt / (double)((size_t)NROWS * DIM);
        out_tail[0] = (float)(1.25 * mean);
        out_tail[1] = (float)exp(-hs);
    }
}

extern "C" void kernel_launch(void* const* d_in, const int* in_sizes, int n_in,
                              void* d_out, int out_size, void* d_ws, size_t ws_size,
                              hipStream_t stream) {
    const float* x  = (const float*)d_in[0];
    const float* cb = (const float*)d_in[1];
    char* ws = (char*)d_ws;
    double* acc            = (double*)ws;                               // 16 B
    unsigned int* ticket   = (unsigned int*)(ws + 16);                  // 4 B
    unsigned int* counts   = (unsigned int*)(ws + 256);                 // 32 KB
    float* cbn             = (float*)(ws + 33024);                      // 32 KB
    unsigned char* xq      = (unsigned char*)(ws + 65792);              // 8 MB fp8 -x
    unsigned char* cbq     = (unsigned char*)(ws + 65792 + 8388608);    // 2 MB fp8 e*8192
    unsigned long long* pp = (unsigned long long*)(ws + 65792 + 8388608 + 2097152); // 1 MB
    double* loss_part      = (double*)(ws + 65792 + 8388608 + 2097152 + 16777216);  // 8 KB
    float* out = (float*)d_out;

    vq_prep       <<<4128, 256, 0, stream>>>(x, xq, cb, cbq, cbn, counts, acc, ticket);
    vq_argmin_mfma<<<512 * NSPLIT, 256, 0, stream>>>(xq, cbq, cbn, pp);
    vq_out        <<<1024, 256, 0, stream>>>(x, cb, pp, out, counts, loss_part);
    vq_fin        <<<32, 256, 0, stream>>>(counts, loss_part, acc, ticket,
                                           out + (size_t)NROWS * DIM);
}